// Round 7
// baseline (396.180 us; speedup 1.0000x reference)
//
#include <hip/hip_runtime.h>
#include <cstdint>
#include <cstddef>

typedef unsigned short u16;
typedef __attribute__((ext_vector_type(4))) float floatx4;
typedef __attribute__((ext_vector_type(8))) __bf16 bf16x8;

// ---------- bf16 helpers ----------
__device__ __forceinline__ float u2f(u16 u) {
    union { unsigned int i; float f; } x;
    x.i = ((unsigned int)u) << 16;
    return x.f;
}
__device__ __forceinline__ u16 f2u(float f) {
    union { float f; unsigned int i; } x;
    x.f = f;
    unsigned int r = x.i + 0x7fffu + ((x.i >> 16) & 1u);   // RNE
    return (u16)(r >> 16);
}

// ---------- merged weight transpose: (K x N) f32 -> (N x K) bf16, 3 weights ----------
__device__ __forceinline__ void tr_tile(const float* __restrict__ in, u16* __restrict__ out,
                                        int K, int N, int bx, int by, float* tile /*32x33*/) {
    int n0 = bx * 32, k0 = by * 32;
    int tx = threadIdx.x & 31, ty = threadIdx.x >> 5;   // ty 0..7
#pragma unroll
    for (int j = 0; j < 4; ++j) {
        int r = ty + j * 8;
        tile[r * 33 + tx] = in[(size_t)(k0 + r) * N + n0 + tx];
    }
    __syncthreads();
#pragma unroll
    for (int j = 0; j < 4; ++j) {
        int r = ty + j * 8;
        out[(size_t)(n0 + r) * K + k0 + tx] = f2u(tile[tx * 33 + r]);
    }
}

__global__ __launch_bounds__(256) void transpose3_kernel(const float* __restrict__ W_in,
                                                         u16* __restrict__ Wt_in,
                                                         const float* __restrict__ Wd,
                                                         u16* __restrict__ Wt_d,
                                                         const float* __restrict__ W_out,
                                                         u16* __restrict__ Wt_out) {
    __shared__ float tile[32 * 33];
    int blk = blockIdx.x;
    if (blk < 4096) {
        tr_tile(W_in, Wt_in, 1024, 4096, blk & 127, blk >> 7, tile);
    } else if (blk < 8192) {
        int b2 = blk - 4096;
        tr_tile(Wd, Wt_d, 2048, 2048, b2 & 63, b2 >> 6, tile);
    } else {
        int b3 = blk - 8192;
        tr_tile(W_out, Wt_out, 2048, 1024, b3 & 31, b3 >> 5, tile);
    }
}

// ---------- layernorm over D=1024 + residual pre-copy (out = x) + delta_acc zero ----------
__global__ __launch_bounds__(256) void ln_kernel(const float* __restrict__ x,
                                                 const float* __restrict__ gamma,
                                                 const float* __restrict__ beta,
                                                 u16* __restrict__ h,
                                                 float* __restrict__ out,
                                                 float* __restrict__ delta_acc) {
    int r = blockIdx.x, t = threadIdx.x;
    if (t == 0) delta_acc[r] = 0.f;
    const float4* xr = (const float4*)(x + (size_t)r * 1024);
    float4 xv = xr[t];
    ((float4*)(out + (size_t)r * 1024))[t] = xv;   // residual base for final atomic GEMM
    float s = xv.x + xv.y + xv.z + xv.w;
    float ss = xv.x * xv.x + xv.y * xv.y + xv.z * xv.z + xv.w * xv.w;
#pragma unroll
    for (int off = 32; off > 0; off >>= 1) {
        s += __shfl_down(s, off, 64);
        ss += __shfl_down(ss, off, 64);
    }
    __shared__ float rs[4], rss[4];
    __shared__ float mu_s, ri_s;
    int wave = t >> 6, lane = t & 63;
    if (lane == 0) { rs[wave] = s; rss[wave] = ss; }
    __syncthreads();
    if (t == 0) {
        float S = rs[0] + rs[1] + rs[2] + rs[3];
        float SS = rss[0] + rss[1] + rss[2] + rss[3];
        float mu = S * (1.f / 1024.f);
        float var = SS * (1.f / 1024.f) - mu * mu;
        mu_s = mu;
        ri_s = rsqrtf(fmaxf(var, 0.f) + 1e-5f);
    }
    __syncthreads();
    float mu = mu_s, ri = ri_s;
    float4 gv = ((const float4*)gamma)[t];
    float4 bv = ((const float4*)beta)[t];
    ushort4 o;
    o.x = f2u((xv.x - mu) * ri * gv.x + bv.x);
    o.y = f2u((xv.y - mu) * ri * gv.y + bv.y);
    o.z = f2u((xv.z - mu) * ri * gv.z + bv.z);
    o.w = f2u((xv.w - mu) * ri * gv.w + bv.w);
    ((ushort4*)(h + (size_t)r * 1024))[t] = o;
}

__device__ __forceinline__ void gl_lds16(const u16* g, u16* l) {
    __builtin_amdgcn_global_load_lds(
        (const __attribute__((address_space(1))) void*)g,
        (__attribute__((address_space(3))) void*)l, 16, 0, 0);
}

// ---------- GEMM1 (xg): 128x128 tile, BK=64, 4 waves x (4x4), bf16 store ----------
__global__ __launch_bounds__(256)
void gemm_xg(const u16* __restrict__ A, const u16* __restrict__ Bt,
             u16* __restrict__ out, int M, int N, int K) {
    __shared__ u16 As[128 * 64];
    __shared__ u16 Bs[128 * 64];
    const int tid = threadIdx.x;
    const int wave = tid >> 6, lane = tid & 63;
    const int row0 = blockIdx.y * 128, col0 = blockIdx.x * 128;
    const int l16 = lane & 15, q = lane >> 4;
    const int sRow = lane >> 2, sK = (lane & 3) * 8;

    floatx4 acc[4][4];
#pragma unroll
    for (int i = 0; i < 4; ++i)
#pragma unroll
        for (int j = 0; j < 4; ++j) acc[i][j] = (floatx4){0.f, 0.f, 0.f, 0.f};

    const u16* gA = A + (size_t)(row0 + wave * 32 + sRow) * K + sK;
    const u16* gB = Bt + (size_t)(col0 + wave * 32 + sRow) * K + sK;
    u16* lA = As + wave * 1024;
    u16* lB = Bs + wave * 1024;
    const int rowb = (wave >> 1) * 64, colb = (wave & 1) * 64;

    for (int k0 = 0; k0 < K; k0 += 64) {
#pragma unroll
        for (int h = 0; h < 2; ++h) {
            gl_lds16(gA + h * 32, lA + h * 4096);
            gl_lds16(gA + (size_t)16 * K + h * 32, lA + h * 4096 + 512);
            gl_lds16(gB + h * 32, lB + h * 4096);
            gl_lds16(gB + (size_t)16 * K + h * 32, lB + h * 4096 + 512);
        }
        gA += 64; gB += 64;
        __syncthreads();
#pragma unroll
        for (int h = 0; h < 2; ++h) {
            bf16x8 af[4], bfr[4];
#pragma unroll
            for (int mi = 0; mi < 4; ++mi)
                af[mi] = *(const bf16x8*)(As + h * 4096 + (rowb + mi * 16 + l16) * 32 + q * 8);
#pragma unroll
            for (int ni = 0; ni < 4; ++ni)
                bfr[ni] = *(const bf16x8*)(Bs + h * 4096 + (colb + ni * 16 + l16) * 32 + q * 8);
#pragma unroll
            for (int mi = 0; mi < 4; ++mi)
#pragma unroll
                for (int ni = 0; ni < 4; ++ni)
                    acc[mi][ni] = __builtin_amdgcn_mfma_f32_16x16x32_bf16(
                        af[mi], bfr[ni], acc[mi][ni], 0, 0, 0);
        }
        __syncthreads();
    }
    const int mB = row0 + rowb, nB = col0 + colb + l16;
#pragma unroll
    for (int mi = 0; mi < 4; ++mi)
#pragma unroll
        for (int ni = 0; ni < 4; ++ni)
#pragma unroll
            for (int rr = 0; rr < 4; ++rr)
                out[(size_t)(mB + mi * 16 + q * 4 + rr) * N + nB + ni * 16] =
                    f2u(acc[mi][ni][rr]);
}

// ---------- 2-wave GEMM body: block 128x64, wave s owns rows s*64..+64 (4x4 acc) ----------
// ratio 8 ds_read : 16 MFMA per K=32 (m97-class); grid preserves 4 blocks/CU.
// EPI 1: atomicAdd per-row sum of softplus(acc + biasf32[col]) into (float*)out
// EPI 4: atomicAdd acc into (float*)out (residual pre-initialized; split-K via blockIdx.z)
template <int EPI>
__device__ __forceinline__
void gemm2w_body(const u16* __restrict__ A, const u16* __restrict__ Bt,
                 void* __restrict__ out, const void* __restrict__ aux,
                 int M, int N, int K, int Ksub) {
    __shared__ u16 As[2 * 128 * 32];   // [h][row][k32]  16 KB
    __shared__ u16 Bs[2 * 64 * 32];    // [h][row][k32]   8 KB
    const int tid = threadIdx.x;
    const int s = tid >> 6, lane = tid & 63;
    const int row0 = blockIdx.y * 128, col0 = blockIdx.x * 64;
    const int koff = blockIdx.z * Ksub;
    const int l16 = lane & 15, q = lane >> 4;
    const int sRow = lane >> 2, sK = (lane & 3) * 8;

    floatx4 acc[4][4];
#pragma unroll
    for (int i = 0; i < 4; ++i)
#pragma unroll
        for (int j = 0; j < 4; ++j) acc[i][j] = (floatx4){0.f, 0.f, 0.f, 0.f};

    // staging: wave s stages A 16-row panels {s*32, s*32+16, (s+2)*32, (s+2)*32+16},
    // B panels {s*32, s*32+16}
    const u16* gA = A + (size_t)(row0 + sRow) * K + koff + sK;
    const u16* gB = Bt + (size_t)(col0 + sRow) * K + koff + sK;
    const int a0 = s * 32, a1 = s * 32 + 16, a2 = (s + 2) * 32, a3 = (s + 2) * 32 + 16;
    const int b0 = s * 32, b1 = s * 32 + 16;

    for (int k0 = 0; k0 < Ksub; k0 += 64) {
#pragma unroll
        for (int h = 0; h < 2; ++h) {
            gl_lds16(gA + (size_t)a0 * K + h * 32, As + h * 4096 + a0 * 32);
            gl_lds16(gA + (size_t)a1 * K + h * 32, As + h * 4096 + a1 * 32);
            gl_lds16(gA + (size_t)a2 * K + h * 32, As + h * 4096 + a2 * 32);
            gl_lds16(gA + (size_t)a3 * K + h * 32, As + h * 4096 + a3 * 32);
            gl_lds16(gB + (size_t)b0 * K + h * 32, Bs + h * 2048 + b0 * 32);
            gl_lds16(gB + (size_t)b1 * K + h * 32, Bs + h * 2048 + b1 * 32);
        }
        gA += 64; gB += 64;
        __syncthreads();
#pragma unroll
        for (int h = 0; h < 2; ++h) {
            bf16x8 af[4], bfr[4];
#pragma unroll
            for (int mi = 0; mi < 4; ++mi)
                af[mi] = *(const bf16x8*)(As + h * 4096 + (s * 64 + mi * 16 + l16) * 32 + q * 8);
#pragma unroll
            for (int ni = 0; ni < 4; ++ni)
                bfr[ni] = *(const bf16x8*)(Bs + h * 2048 + (ni * 16 + l16) * 32 + q * 8);
#pragma unroll
            for (int mi = 0; mi < 4; ++mi)
#pragma unroll
                for (int ni = 0; ni < 4; ++ni)
                    acc[mi][ni] = __builtin_amdgcn_mfma_f32_16x16x32_bf16(
                        af[mi], bfr[ni], acc[mi][ni], 0, 0, 0);
        }
        __syncthreads();
    }

    const int mB = row0 + s * 64;
    const int nB = col0 + l16;
    if constexpr (EPI == 1) {
        float* dacc = (float*)out;
        const float* bias = (const float*)aux;
#pragma unroll
        for (int mi = 0; mi < 4; ++mi) {
#pragma unroll
            for (int rr = 0; rr < 4; ++rr) {
                float sv = 0.f;
#pragma unroll
                for (int ni = 0; ni < 4; ++ni) {
                    float t2 = acc[mi][ni][rr] + bias[nB + ni * 16];
                    sv += (t2 > 20.f) ? t2 : log1pf(expf(t2));
                }
#pragma unroll
                for (int off = 1; off < 16; off <<= 1)
                    sv += __shfl_xor(sv, off, 64);
                if (l16 == 0)
                    atomicAdd(&dacc[mB + mi * 16 + q * 4 + rr], sv);
            }
        }
    } else {
        float* C = (float*)out;
#pragma unroll
        for (int mi = 0; mi < 4; ++mi)
#pragma unroll
            for (int ni = 0; ni < 4; ++ni)
#pragma unroll
                for (int rr = 0; rr < 4; ++rr)
                    atomicAdd(&C[(size_t)(mB + mi * 16 + q * 4 + rr) * N + nB + ni * 16],
                              acc[mi][ni][rr]);
    }
}

__global__ __launch_bounds__(128)
void gemm_delta(const u16* __restrict__ A, const u16* __restrict__ Bt,
                void* __restrict__ out, const void* __restrict__ aux,
                int M, int N, int K, int Ksub) {
    gemm2w_body<1>(A, Bt, out, aux, M, N, K, Ksub);
}

__global__ __launch_bounds__(128)
void gemm_out(const u16* __restrict__ A, const u16* __restrict__ Bt,
              void* __restrict__ out, const void* __restrict__ aux,
              int M, int N, int K, int Ksub) {
    gemm2w_body<4>(A, Bt, out, aux, M, N, K, Ksub);
}

// ---------- fused conv(K=4)+SiLU+Bdot, 8 rows/block (xg re-read 4x -> 1.4x) ----------
__global__ __launch_bounds__(256) void conv_bxda_kernel(const u16* __restrict__ xg,
                                                        const float* __restrict__ conv_w,
                                                        const float* __restrict__ conv_b,
                                                        const float* __restrict__ B_mat,
                                                        u16* __restrict__ xsc,
                                                        float* __restrict__ Bdotn) {
    int r0 = blockIdx.x * 8;                  // 8 rows per block; 2048 % 8 == 0 so no
    int l0 = r0 & 2047, bb = r0 >> 11;        // batch-boundary crossing
    int t = threadIdx.x, d8 = t * 8;
    int wave = t >> 6, lane = t & 63;

    // stage 11 input rows (l0-3 .. l0+7) x 8 cols as raw bf16
    ushort4 rw[11][2];
#pragma unroll
    for (int j = 0; j < 11; ++j) {
        int ls = l0 + j - 3;
        if (ls >= 0) {
            const u16* row = xg + (size_t)((bb << 11) + ls) * 4096 + d8;
            rw[j][0] = *(const ushort4*)row;
            rw[j][1] = *(const ushort4*)(row + 4);
        } else {
            rw[j][0] = (ushort4){0, 0, 0, 0};
            rw[j][1] = (ushort4){0, 0, 0, 0};
        }
    }
    float w[8][4];
#pragma unroll
    for (int j = 0; j < 8; ++j) {
        float4 wv = *(const float4*)(conv_w + (size_t)(d8 + j) * 4);
        w[j][0] = wv.x; w[j][1] = wv.y; w[j][2] = wv.z; w[j][3] = wv.w;
    }
    float cb[8];
    {
        float4 b0 = *(const float4*)(conv_b + d8);
        float4 b1 = *(const float4*)(conv_b + d8 + 4);
        cb[0] = b0.x; cb[1] = b0.y; cb[2] = b0.z; cb[3] = b0.w;
        cb[4] = b1.x; cb[5] = b1.y; cb[6] = b1.z; cb[7] = b1.w;
    }

    // conv + silu for the 8 rows, keep results (bf16-rounded) in regs
    float xs8[8][8];
#pragma unroll
    for (int i = 0; i < 8; ++i) {
        float xs[8];
#pragma unroll
        for (int j = 0; j < 8; ++j) xs[j] = cb[j];
#pragma unroll
        for (int k = 0; k < 4; ++k) {
            ushort4 u0 = rw[i + k][0], u1 = rw[i + k][1];
            xs[0] += w[0][k] * u2f(u0.x); xs[1] += w[1][k] * u2f(u0.y);
            xs[2] += w[2][k] * u2f(u0.z); xs[3] += w[3][k] * u2f(u0.w);
            xs[4] += w[4][k] * u2f(u1.x); xs[5] += w[5][k] * u2f(u1.y);
            xs[6] += w[6][k] * u2f(u1.z); xs[7] += w[7][k] * u2f(u1.w);
        }
        ushort4 o0, o1;
#pragma unroll
        for (int j = 0; j < 8; ++j) {
            float v = xs[j] / (1.f + expf(-xs[j]));
            u16 uv = f2u(v);
            xs8[i][j] = u2f(uv);   // bf16-rounded so Bdot matches stored xsc
            if (j == 0) o0.x = uv; else if (j == 1) o0.y = uv;
            else if (j == 2) o0.z = uv; else if (j == 3) o0.w = uv;
            else if (j == 4) o1.x = uv; else if (j == 5) o1.y = uv;
            else if (j == 6) o1.z = uv; else o1.w = uv;
        }
        u16* orow = xsc + (size_t)(r0 + i) * 2048 + d8;
        *(ushort4*)orow = o0;
        *(ushort4*)(orow + 4) = o1;
    }

    // Bdot: n outer (B_mat loaded once per n), 8 rows inner
    __shared__ float pn[4][16][8];
#pragma unroll
    for (int n = 0; n < 16; ++n) {
        const float* br = B_mat + (size_t)n * 2048 + d8;
        float4 c0 = *(const float4*)br;
        float4 c1 = *(const float4*)(br + 4);
#pragma unroll
        for (int i = 0; i < 8; ++i) {
            float a = xs8[i][0] * c0.x + xs8[i][1] * c0.y + xs8[i][2] * c0.z + xs8[i][3] * c0.w
                    + xs8[i][4] * c1.x + xs8[i][5] * c1.y + xs8[i][6] * c1.z + xs8[i][7] * c1.w;
#pragma unroll
            for (int off = 1; off < 64; off <<= 1)
                a += __shfl_xor(a, off, 64);
            if (lane == 0) pn[wave][n][i] = a;
        }
    }
    __syncthreads();
    if (t < 128) {
        int n = t >> 3, i = t & 7;
        Bdotn[(size_t)n * 4096 + r0 + i] =
            pn[0][n][i] + pn[1][n][i] + pn[2][n][i] + pn[3][n][i];
    }
}

// ---------- selective scan: 32 chains, 1 wave each; n-major I/O, LDS-coalesced ----------
__global__ __launch_bounds__(64) void scan_kernel(const float* __restrict__ delta_acc,
                                                  const float* __restrict__ Bdotn,
                                                  const float* __restrict__ A_log,
                                                  float* __restrict__ hsn) {
    int chain = blockIdx.x;                 // 0..31
    int b = chain >> 4, n = chain & 15;
    int j = threadIdx.x;                    // 0..63
    __shared__ float sd[2048], sb[2048];
#pragma unroll
    for (int m = 0; m < 8; ++m) {
        int idx = (m * 64 + j) * 4;
        *(float4*)(sd + idx) = *(const float4*)(delta_acc + b * 2048 + idx);
        *(float4*)(sb + idx) = *(const float4*)(Bdotn + (size_t)n * 4096 + b * 2048 + idx);
    }
    __syncthreads();
    float An = -expf(A_log[n]);
    float a[32], bb[32];
#pragma unroll
    for (int i = 0; i < 32; ++i) {
        float dl = sd[j * 32 + i] * (1.f / 2048.f);
        a[i] = expf(dl * An);
        bb[i] = sb[j * 32 + i] * dl;
    }
    float Aacc = 1.f, Bacc = 0.f;
#pragma unroll
    for (int i = 0; i < 32; ++i) {
        Bacc = a[i] * Bacc + bb[i];
        Aacc = a[i] * Aacc;
    }
#pragma unroll
    for (int d = 1; d < 64; d <<= 1) {
        float Ap = __shfl_up(Aacc, d, 64);
        float Bp = __shfl_up(Bacc, d, 64);
        if (j >= d) {
            Bacc = Aacc * Bp + Bacc;
            Aacc = Aacc * Ap;
        }
    }
    float hstart = __shfl_up(Bacc, 1, 64);
    if (j == 0) hstart = 0.f;
    float h = hstart;
    __syncthreads();
#pragma unroll
    for (int i = 0; i < 32; ++i) {
        h = a[i] * h + bb[i];
        sd[j * 32 + i] = h;
    }
    __syncthreads();
#pragma unroll
    for (int m = 0; m < 8; ++m) {
        int idx = (m * 64 + j) * 4;
        *(float4*)(hsn + (size_t)n * 4096 + b * 2048 + idx) = *(const float4*)(sd + idx);
    }
}

// ---------- ymid = (hs·C_mat[d,:] + D_vec*xsc) * silu(gate), bf16 out ----------
__global__ __launch_bounds__(256) void ymid_kernel(const float* __restrict__ hsn,
                                                   const float* __restrict__ C_mat,
                                                   const float* __restrict__ D_vec,
                                                   const u16* __restrict__ xsc,
                                                   const u16* __restrict__ xg,
                                                   u16* __restrict__ ymid) {
    int r = blockIdx.y;
    int d = blockIdx.x * 256 + threadIdx.x;
    __shared__ float hsv[16];
    if (threadIdx.x < 16) hsv[threadIdx.x] = hsn[(size_t)threadIdx.x * 4096 + r];
    __syncthreads();
    const float* crow = C_mat + (size_t)d * 16;
    float acc = 0.f;
#pragma unroll
    for (int n = 0; n < 16; ++n) acc += hsv[n] * crow[n];
    float xv = u2f(xsc[(size_t)r * 2048 + d]);
    float g = u2f(xg[(size_t)r * 4096 + 2048 + d]);
    float y = acc + D_vec[d] * xv;
    y *= g / (1.f + expf(-g));
    ymid[(size_t)r * 2048 + d] = f2u(y);
}

extern "C" void kernel_launch(void* const* d_in, const int* in_sizes, int n_in,
                              void* d_out, int out_size, void* d_ws, size_t ws_size,
                              hipStream_t stream) {
    (void)in_sizes; (void)n_in;
    const float* x      = (const float*)d_in[0];
    const float* ln_g   = (const float*)d_in[1];
    const float* ln_b   = (const float*)d_in[2];
    const float* W_in   = (const float*)d_in[3];
    const float* conv_w = (const float*)d_in[4];
    const float* conv_b = (const float*)d_in[5];
    const float* A_log  = (const float*)d_in[6];
    const float* B_mat  = (const float*)d_in[7];
    const float* C_mat  = (const float*)d_in[8];
    const float* D_vec  = (const float*)d_in[9];
    const float* Wd     = (const float*)d_in[10];
    const float* bd     = (const float*)d_in[11];
    const float* W_out  = (const float*)d_in[12];
    float* out = (float*)d_out;

    // ---- workspace layout (time-overlaid), ~76.5 MiB ----
    char* base = (char*)d_ws;
    u16* Wt_in  = (u16*)base;                          // 4096x1024 bf16 (bufA lo)
    u16* h_ln   = (u16*)base + 4096ull * 1024;         // 4096x1024 bf16 (bufA hi)
    u16* ymid   = (u16*)base;                          // 4096x2048 bf16 (reuse bufA post-GEMM1)
    u16* Wt_d   = (u16*)(base + (16ull << 20));        // 2048x2048 bf16 (bufB)
    u16* Wt_out = (u16*)(base + (24ull << 20));        // 1024x2048 bf16 (4 MiB)
    u16* xg     = (u16*)(base + (28ull << 20));        // 4096x4096 bf16 (32 MiB)
    u16* xsc    = (u16*)(base + (60ull << 20));        // 4096x2048 bf16 (16 MiB)
    float* delta_acc = (float*)(base + (76ull << 20)); // 4096 f32
    float* Bdotn = delta_acc + 4096;                   // [16][4096] f32
    float* hsn   = Bdotn + 16 * 4096;                  // [16][4096] f32
    size_t needed = (76ull << 20) + 4096ull * 4 * (1 + 2 * 16);

    if (needed > ws_size) {
        hipMemsetAsync(d_out, 0x7F, (size_t)out_size * 4, stream);  // finite sentinel 3.39e38
        return;
    }

    // 1. all weight transposes (one launch)
    transpose3_kernel<<<10240, 256, 0, stream>>>(W_in, Wt_in, Wd, Wt_d, W_out, Wt_out);
    // 2. layernorm + out=x residual pre-copy + delta_acc zero
    ln_kernel<<<4096, 256, 0, stream>>>(x, ln_g, ln_b, h_ln, out, delta_acc);
    // 3. xg = h @ W_in   128x128 tile, grid 1024
    gemm_xg<<<dim3(32, 32), 256, 0, stream>>>(h_ln, Wt_in, xg, 4096, 4096, 1024);
    // 4. fused conv + silu + B-dots (8 rows/block)
    conv_bxda_kernel<<<512, 256, 0, stream>>>(xg, conv_w, conv_b, B_mat, xsc, Bdotn);
    // 5. delta GEMM: 2-wave 128x64 blocks, grid 1024, 4 blocks/CU
    gemm_delta<<<dim3(32, 32, 1), 128, 0, stream>>>(xsc, Wt_d, delta_acc, bd,
                                                    4096, 2048, 2048, 2048);
    // 6. selective scan
    scan_kernel<<<32, 64, 0, stream>>>(delta_acc, Bdotn, A_log, hsn);
    // 7. ymid (into bufA; h_ln/Wt_in dead)
    ymid_kernel<<<dim3(8, 4096), 256, 0, stream>>>(hsn, C_mat, D_vec, xsc, xg, ymid);
    // 8. out += ymid @ W_out : 2-wave 128x64 blocks, split-K=2 atomics, grid 1024
    gemm_out<<<dim3(16, 32, 2), 128, 0, stream>>>(ymid, Wt_out, out, nullptr,
                                                  4096, 1024, 2048, 1024);
}

// Round 8
// 369.886 us; speedup vs baseline: 1.0711x; 1.0711x over previous
//
#include <hip/hip_runtime.h>
#include <cstdint>
#include <cstddef>

typedef unsigned short u16;
typedef __attribute__((ext_vector_type(4))) float floatx4;
typedef __attribute__((ext_vector_type(8))) __bf16 bf16x8;

// ---------- bf16 helpers ----------
__device__ __forceinline__ float u2f(u16 u) {
    union { unsigned int i; float f; } x;
    x.i = ((unsigned int)u) << 16;
    return x.f;
}
__device__ __forceinline__ u16 f2u(float f) {
    union { float f; unsigned int i; } x;
    x.f = f;
    unsigned int r = x.i + 0x7fffu + ((x.i >> 16) & 1u);   // RNE
    return (u16)(r >> 16);
}

// ---------- prep: 3 weight transposes + B_mat cast-copy/pad + layernorm(+out=x) ----------
__device__ __forceinline__ void tr_tile(const float* __restrict__ in, u16* __restrict__ out,
                                        int K, int N, int bx, int by, float* tile /*32x33*/) {
    int n0 = bx * 32, k0 = by * 32;
    int tx = threadIdx.x & 31, ty = threadIdx.x >> 5;   // ty 0..7
#pragma unroll
    for (int j = 0; j < 4; ++j) {
        int r = ty + j * 8;
        tile[r * 33 + tx] = in[(size_t)(k0 + r) * N + n0 + tx];
    }
    __syncthreads();
#pragma unroll
    for (int j = 0; j < 4; ++j) {
        int r = ty + j * 8;
        out[(size_t)(n0 + r) * K + k0 + tx] = f2u(tile[tx * 33 + r]);
    }
}

// blocks: [0,4096) W_in tr; [4096,8192) Wd tr (rows 0..2047 of Wt_ext);
//         [8192,10240) W_out tr; [10240,14336) layernorm; [14336,14848) B_mat copy+pad
__global__ __launch_bounds__(256)
void prep_kernel(const float* __restrict__ W_in, u16* __restrict__ Wt_in,
                 const float* __restrict__ Wd, u16* __restrict__ Wt_ext,
                 const float* __restrict__ W_out, u16* __restrict__ Wt_out,
                 const float* __restrict__ B_mat,
                 const float* __restrict__ x, const float* __restrict__ gamma,
                 const float* __restrict__ beta, u16* __restrict__ h,
                 float* __restrict__ out) {
    __shared__ float tile[32 * 33];
    int blk = blockIdx.x, t = threadIdx.x;
    if (blk < 4096) {
        tr_tile(W_in, Wt_in, 1024, 4096, blk & 127, blk >> 7, tile);
    } else if (blk < 8192) {
        int b2 = blk - 4096;
        tr_tile(Wd, Wt_ext, 2048, 2048, b2 & 63, b2 >> 6, tile);
    } else if (blk < 10240) {
        int b3 = blk - 8192;
        tr_tile(W_out, Wt_out, 2048, 1024, b3 & 31, b3 >> 5, tile);
    } else if (blk < 14336) {
        int r = blk - 10240;
        const float4* xr = (const float4*)(x + (size_t)r * 1024);
        float4 xv = xr[t];
        ((float4*)(out + (size_t)r * 1024))[t] = xv;   // residual base for atomic GEMM3
        float s = xv.x + xv.y + xv.z + xv.w;
        float ss = xv.x * xv.x + xv.y * xv.y + xv.z * xv.z + xv.w * xv.w;
#pragma unroll
        for (int off = 32; off > 0; off >>= 1) {
            s += __shfl_down(s, off, 64);
            ss += __shfl_down(ss, off, 64);
        }
        __shared__ float rs[4], rss[4], mu_s, ri_s;
        int wave = t >> 6, lane = t & 63;
        if (lane == 0) { rs[wave] = s; rss[wave] = ss; }
        __syncthreads();
        if (t == 0) {
            float S = rs[0] + rs[1] + rs[2] + rs[3];
            float SS = rss[0] + rss[1] + rss[2] + rss[3];
            float mu = S * (1.f / 1024.f);
            float var = SS * (1.f / 1024.f) - mu * mu;
            mu_s = mu;
            ri_s = rsqrtf(fmaxf(var, 0.f) + 1e-5f);
        }
        __syncthreads();
        float mu = mu_s, ri = ri_s;
        float4 gv = ((const float4*)gamma)[t];
        float4 bv = ((const float4*)beta)[t];
        ushort4 o;
        o.x = f2u((xv.x - mu) * ri * gv.x + bv.x);
        o.y = f2u((xv.y - mu) * ri * gv.y + bv.y);
        o.z = f2u((xv.z - mu) * ri * gv.z + bv.z);
        o.w = f2u((xv.w - mu) * ri * gv.w + bv.w);
        ((ushort4*)(h + (size_t)r * 1024))[t] = o;
    } else {
        // Wt_ext rows 2048..2111: first 16 = B_mat (bf16 cast), rest zero pad
        int idx = (blk - 14336) * 256 + t;         // 0..131071
        int row = 2048 + (idx >> 11), col = idx & 2047;
        u16 v = (row < 2064) ? f2u(B_mat[(size_t)(row - 2048) * 2048 + col]) : (u16)0;
        Wt_ext[(size_t)row * 2048 + col] = v;
    }
}

__device__ __forceinline__ void gl_lds16(const u16* g, u16* l) {
    __builtin_amdgcn_global_load_lds(
        (const __attribute__((address_space(1))) void*)g,
        (__attribute__((address_space(3))) void*)l, 16, 0, 0);
}

// ---------- GEMM1 (xg): 128x128 tile, BK=64, 4 waves x (4x4), bf16 store ----------
__global__ __launch_bounds__(256)
void gemm_xg(const u16* __restrict__ A, const u16* __restrict__ Bt,
             u16* __restrict__ out, int M, int N, int K) {
    __shared__ u16 As[128 * 64];
    __shared__ u16 Bs[128 * 64];
    const int tid = threadIdx.x;
    const int wave = tid >> 6, lane = tid & 63;
    const int row0 = blockIdx.y * 128, col0 = blockIdx.x * 128;
    const int l16 = lane & 15, q = lane >> 4;
    const int sRow = lane >> 2, sK = (lane & 3) * 8;

    floatx4 acc[4][4];
#pragma unroll
    for (int i = 0; i < 4; ++i)
#pragma unroll
        for (int j = 0; j < 4; ++j) acc[i][j] = (floatx4){0.f, 0.f, 0.f, 0.f};

    const u16* gA = A + (size_t)(row0 + wave * 32 + sRow) * K + sK;
    const u16* gB = Bt + (size_t)(col0 + wave * 32 + sRow) * K + sK;
    u16* lA = As + wave * 1024;
    u16* lB = Bs + wave * 1024;
    const int rowb = (wave >> 1) * 64, colb = (wave & 1) * 64;

    for (int k0 = 0; k0 < K; k0 += 64) {
#pragma unroll
        for (int h = 0; h < 2; ++h) {
            gl_lds16(gA + h * 32, lA + h * 4096);
            gl_lds16(gA + (size_t)16 * K + h * 32, lA + h * 4096 + 512);
            gl_lds16(gB + h * 32, lB + h * 4096);
            gl_lds16(gB + (size_t)16 * K + h * 32, lB + h * 4096 + 512);
        }
        gA += 64; gB += 64;
        __syncthreads();
#pragma unroll
        for (int h = 0; h < 2; ++h) {
            bf16x8 af[4], bfr[4];
#pragma unroll
            for (int mi = 0; mi < 4; ++mi)
                af[mi] = *(const bf16x8*)(As + h * 4096 + (rowb + mi * 16 + l16) * 32 + q * 8);
#pragma unroll
            for (int ni = 0; ni < 4; ++ni)
                bfr[ni] = *(const bf16x8*)(Bs + h * 4096 + (colb + ni * 16 + l16) * 32 + q * 8);
#pragma unroll
            for (int mi = 0; mi < 4; ++mi)
#pragma unroll
                for (int ni = 0; ni < 4; ++ni)
                    acc[mi][ni] = __builtin_amdgcn_mfma_f32_16x16x32_bf16(
                        af[mi], bfr[ni], acc[mi][ni], 0, 0, 0);
        }
        __syncthreads();
    }
    const int mB = row0 + rowb, nB = col0 + colb + l16;
#pragma unroll
    for (int mi = 0; mi < 4; ++mi)
#pragma unroll
        for (int ni = 0; ni < 4; ++ni)
#pragma unroll
            for (int rr = 0; rr < 4; ++rr)
                out[(size_t)(mB + mi * 16 + q * 4 + rr) * N + nB + ni * 16] =
                    f2u(acc[mi][ni][rr]);
}

// ---------- round-6 4-wave GEMM, BK=64, tile 128x64 (44-VGPR config) ----------
// EPI 1: delta fusion + Bdot col-block (blockIdx.x==Nwd/64 stores raw acc to Bdotn)
// EPI 4: atomicAdd acc into (float*)out (residual pre-initialized; split-K via z)
template <int EPI>
__global__ __launch_bounds__(256)
void gemm_n64(const u16* __restrict__ A, const u16* __restrict__ Bt,
              void* __restrict__ out, const void* __restrict__ aux,
              float* __restrict__ Bdotn,
              int M, int N, int K, int Ksub) {
    __shared__ u16 As[128 * 64];
    __shared__ u16 Bs[64 * 64];
    const int tid = threadIdx.x;
    const int wave = tid >> 6, lane = tid & 63;
    const int row0 = blockIdx.y * 128, col0 = blockIdx.x * 64;
    const int koff = blockIdx.z * Ksub;
    const int l16 = lane & 15, q = lane >> 4;
    const int sRow = lane >> 2, sK = (lane & 3) * 8;

    floatx4 acc[2][4];
#pragma unroll
    for (int i = 0; i < 2; ++i)
#pragma unroll
        for (int j = 0; j < 4; ++j) acc[i][j] = (floatx4){0.f, 0.f, 0.f, 0.f};

    const u16* gA = A + (size_t)(row0 + wave * 32 + sRow) * K + koff + sK;
    const u16* gB = Bt + (size_t)(col0 + wave * 16 + sRow) * K + koff + sK;
    u16* lA = As + wave * 1024;
    u16* lB = Bs + wave * 512;
    const int rowb = wave * 32;

    for (int k0 = 0; k0 < Ksub; k0 += 64) {
#pragma unroll
        for (int h = 0; h < 2; ++h) {
            gl_lds16(gA + h * 32, lA + h * 4096);
            gl_lds16(gA + (size_t)16 * K + h * 32, lA + h * 4096 + 512);
            gl_lds16(gB + h * 32, lB + h * 2048);
        }
        gA += 64; gB += 64;
        __syncthreads();
#pragma unroll
        for (int h = 0; h < 2; ++h) {
            bf16x8 af[2], bfr[4];
#pragma unroll
            for (int mi = 0; mi < 2; ++mi)
                af[mi] = *(const bf16x8*)(As + h * 4096 + (rowb + mi * 16 + l16) * 32 + q * 8);
#pragma unroll
            for (int ni = 0; ni < 4; ++ni)
                bfr[ni] = *(const bf16x8*)(Bs + h * 2048 + (ni * 16 + l16) * 32 + q * 8);
#pragma unroll
            for (int mi = 0; mi < 2; ++mi)
#pragma unroll
                for (int ni = 0; ni < 4; ++ni)
                    acc[mi][ni] = __builtin_amdgcn_mfma_f32_16x16x32_bf16(
                        af[mi], bfr[ni], acc[mi][ni], 0, 0, 0);
        }
        __syncthreads();
    }

    const int mB = row0 + rowb;
    const int nB = col0 + l16;
    if constexpr (EPI == 1) {
        if (col0 < 2048) {
            // delta fusion: per-row sum of softplus(acc + bias)
            float* dacc = (float*)out;
            const float* bias = (const float*)aux;
#pragma unroll
            for (int mi = 0; mi < 2; ++mi) {
#pragma unroll
                for (int rr = 0; rr < 4; ++rr) {
                    float sv = 0.f;
#pragma unroll
                    for (int ni = 0; ni < 4; ++ni) {
                        float t2 = acc[mi][ni][rr] + bias[nB + ni * 16];
                        sv += (t2 > 20.f) ? t2 : log1pf(expf(t2));
                    }
#pragma unroll
                    for (int off = 1; off < 16; off <<= 1)
                        sv += __shfl_xor(sv, off, 64);
                    if (l16 == 0)
                        atomicAdd(&dacc[mB + mi * 16 + q * 4 + rr], sv);
                }
            }
        } else {
            // Bdot col-block: local n = l16 (ni==0 only); raw dot, n-major store
#pragma unroll
            for (int mi = 0; mi < 2; ++mi)
#pragma unroll
                for (int rr = 0; rr < 4; ++rr)
                    Bdotn[(size_t)l16 * 4096 + mB + mi * 16 + q * 4 + rr] =
                        acc[mi][0][rr];
        }
    } else {
        float* C = (float*)out;
#pragma unroll
        for (int mi = 0; mi < 2; ++mi)
#pragma unroll
            for (int ni = 0; ni < 4; ++ni)
#pragma unroll
                for (int rr = 0; rr < 4; ++rr)
                    atomicAdd(&C[(size_t)(mB + mi * 16 + q * 4 + rr) * N + nB + ni * 16],
                              acc[mi][ni][rr]);
    }
}

// ---------- lean conv(K=4)+SiLU, 8 rows/block + delta_acc zero ----------
__global__ __launch_bounds__(256) void conv_silu_kernel(const u16* __restrict__ xg,
                                                        const float* __restrict__ conv_w,
                                                        const float* __restrict__ conv_b,
                                                        u16* __restrict__ xsc,
                                                        float* __restrict__ delta_acc) {
    int r0 = blockIdx.x * 8;                  // 8 rows/block; 2048 % 8 == 0
    int l0 = r0 & 2047, bb = r0 >> 11;
    int t = threadIdx.x, d8 = t * 8;
    if (t < 8) delta_acc[r0 + t] = 0.f;       // zero before gemm_delta's atomics

    ushort4 rw[11][2];
#pragma unroll
    for (int j = 0; j < 11; ++j) {
        int ls = l0 + j - 3;
        if (ls >= 0) {
            const u16* row = xg + (size_t)((bb << 11) + ls) * 4096 + d8;
            rw[j][0] = *(const ushort4*)row;
            rw[j][1] = *(const ushort4*)(row + 4);
        } else {
            rw[j][0] = (ushort4){0, 0, 0, 0};
            rw[j][1] = (ushort4){0, 0, 0, 0};
        }
    }
    float w[8][4];
#pragma unroll
    for (int j = 0; j < 8; ++j) {
        float4 wv = *(const float4*)(conv_w + (size_t)(d8 + j) * 4);
        w[j][0] = wv.x; w[j][1] = wv.y; w[j][2] = wv.z; w[j][3] = wv.w;
    }
    float cb[8];
    {
        float4 b0 = *(const float4*)(conv_b + d8);
        float4 b1 = *(const float4*)(conv_b + d8 + 4);
        cb[0] = b0.x; cb[1] = b0.y; cb[2] = b0.z; cb[3] = b0.w;
        cb[4] = b1.x; cb[5] = b1.y; cb[6] = b1.z; cb[7] = b1.w;
    }
#pragma unroll
    for (int i = 0; i < 8; ++i) {
        float xs[8];
#pragma unroll
        for (int j = 0; j < 8; ++j) xs[j] = cb[j];
#pragma unroll
        for (int k = 0; k < 4; ++k) {
            ushort4 u0 = rw[i + k][0], u1 = rw[i + k][1];
            xs[0] += w[0][k] * u2f(u0.x); xs[1] += w[1][k] * u2f(u0.y);
            xs[2] += w[2][k] * u2f(u0.z); xs[3] += w[3][k] * u2f(u0.w);
            xs[4] += w[4][k] * u2f(u1.x); xs[5] += w[5][k] * u2f(u1.y);
            xs[6] += w[6][k] * u2f(u1.z); xs[7] += w[7][k] * u2f(u1.w);
        }
        ushort4 o0, o1;
        o0.x = f2u(xs[0] / (1.f + expf(-xs[0])));
        o0.y = f2u(xs[1] / (1.f + expf(-xs[1])));
        o0.z = f2u(xs[2] / (1.f + expf(-xs[2])));
        o0.w = f2u(xs[3] / (1.f + expf(-xs[3])));
        o1.x = f2u(xs[4] / (1.f + expf(-xs[4])));
        o1.y = f2u(xs[5] / (1.f + expf(-xs[5])));
        o1.z = f2u(xs[6] / (1.f + expf(-xs[6])));
        o1.w = f2u(xs[7] / (1.f + expf(-xs[7])));
        u16* orow = xsc + (size_t)(r0 + i) * 2048 + d8;
        *(ushort4*)orow = o0;
        *(ushort4*)(orow + 4) = o1;
    }
}

// ---------- selective scan: 32 chains, 1 wave each; n-major I/O, LDS-coalesced ----------
__global__ __launch_bounds__(64) void scan_kernel(const float* __restrict__ delta_acc,
                                                  const float* __restrict__ Bdotn,
                                                  const float* __restrict__ A_log,
                                                  float* __restrict__ hsn) {
    int chain = blockIdx.x;                 // 0..31
    int b = chain >> 4, n = chain & 15;
    int j = threadIdx.x;                    // 0..63
    __shared__ float sd[2048], sb[2048];
#pragma unroll
    for (int m = 0; m < 8; ++m) {
        int idx = (m * 64 + j) * 4;
        *(float4*)(sd + idx) = *(const float4*)(delta_acc + b * 2048 + idx);
        *(float4*)(sb + idx) = *(const float4*)(Bdotn + (size_t)n * 4096 + b * 2048 + idx);
    }
    __syncthreads();
    float An = -expf(A_log[n]);
    float a[32], bb[32];
#pragma unroll
    for (int i = 0; i < 32; ++i) {
        float dl = sd[j * 32 + i] * (1.f / 2048.f);
        a[i] = expf(dl * An);
        bb[i] = sb[j * 32 + i] * dl;
    }
    float Aacc = 1.f, Bacc = 0.f;
#pragma unroll
    for (int i = 0; i < 32; ++i) {
        Bacc = a[i] * Bacc + bb[i];
        Aacc = a[i] * Aacc;
    }
#pragma unroll
    for (int d = 1; d < 64; d <<= 1) {
        float Ap = __shfl_up(Aacc, d, 64);
        float Bp = __shfl_up(Bacc, d, 64);
        if (j >= d) {
            Bacc = Aacc * Bp + Bacc;
            Aacc = Aacc * Ap;
        }
    }
    float hstart = __shfl_up(Bacc, 1, 64);
    if (j == 0) hstart = 0.f;
    float h = hstart;
    __syncthreads();
#pragma unroll
    for (int i = 0; i < 32; ++i) {
        h = a[i] * h + bb[i];
        sd[j * 32 + i] = h;
    }
    __syncthreads();
#pragma unroll
    for (int m = 0; m < 8; ++m) {
        int idx = (m * 64 + j) * 4;
        *(float4*)(hsn + (size_t)n * 4096 + b * 2048 + idx) = *(const float4*)(sd + idx);
    }
}

// ---------- ymid = (hs·C_mat[d,:] + D_vec*xsc) * silu(gate), bf16 out ----------
__global__ __launch_bounds__(256) void ymid_kernel(const float* __restrict__ hsn,
                                                   const float* __restrict__ C_mat,
                                                   const float* __restrict__ D_vec,
                                                   const u16* __restrict__ xsc,
                                                   const u16* __restrict__ xg,
                                                   u16* __restrict__ ymid) {
    int r = blockIdx.y;
    int d = blockIdx.x * 256 + threadIdx.x;
    __shared__ float hsv[16];
    if (threadIdx.x < 16) hsv[threadIdx.x] = hsn[(size_t)threadIdx.x * 4096 + r];
    __syncthreads();
    const float* crow = C_mat + (size_t)d * 16;
    float acc = 0.f;
#pragma unroll
    for (int n = 0; n < 16; ++n) acc += hsv[n] * crow[n];
    float xv = u2f(xsc[(size_t)r * 2048 + d]);
    float g = u2f(xg[(size_t)r * 4096 + 2048 + d]);
    float y = acc + D_vec[d] * xv;
    y *= g / (1.f + expf(-g));
    ymid[(size_t)r * 2048 + d] = f2u(y);
}

extern "C" void kernel_launch(void* const* d_in, const int* in_sizes, int n_in,
                              void* d_out, int out_size, void* d_ws, size_t ws_size,
                              hipStream_t stream) {
    (void)in_sizes; (void)n_in;
    const float* x      = (const float*)d_in[0];
    const float* ln_g   = (const float*)d_in[1];
    const float* ln_b   = (const float*)d_in[2];
    const float* W_in   = (const float*)d_in[3];
    const float* conv_w = (const float*)d_in[4];
    const float* conv_b = (const float*)d_in[5];
    const float* A_log  = (const float*)d_in[6];
    const float* B_mat  = (const float*)d_in[7];
    const float* C_mat  = (const float*)d_in[8];
    const float* D_vec  = (const float*)d_in[9];
    const float* Wd     = (const float*)d_in[10];
    const float* bd     = (const float*)d_in[11];
    const float* W_out  = (const float*)d_in[12];
    float* out = (float*)d_out;

    // ---- workspace layout (time-overlaid), ~77.1 MiB ----
    char* base = (char*)d_ws;
    u16* Wt_in  = (u16*)base;                          // 4096x1024 bf16 (bufA lo)
    u16* h_ln   = (u16*)base + 4096ull * 1024;         // 4096x1024 bf16 (bufA hi)
    u16* ymid   = (u16*)base;                          // 4096x2048 bf16 (reuse bufA post-GEMM1)
    u16* Wt_ext = (u16*)(base + (16ull << 20));        // 2112x2048 bf16 (Wd^T + B_mat + pad)
    u16* Wt_out = (u16*)(base + (25ull << 20));        // 1024x2048 bf16 (4 MiB)
    u16* xg     = (u16*)(base + (29ull << 20));        // 4096x4096 bf16 (32 MiB)
    u16* xsc    = (u16*)(base + (61ull << 20));        // 4096x2048 bf16 (16 MiB)
    float* delta_acc = (float*)(base + (77ull << 20)); // 4096 f32
    float* Bdotn = delta_acc + 4096;                   // [16][4096] f32
    float* hsn   = Bdotn + 16 * 4096;                  // [16][4096] f32
    size_t needed = (77ull << 20) + 4096ull * 4 * (1 + 2 * 16);

    if (needed > ws_size) {
        hipMemsetAsync(d_out, 0x7F, (size_t)out_size * 4, stream);  // finite sentinel 3.39e38
        return;
    }

    // 1. prep: transposes + B_mat rows + layernorm + out=x
    prep_kernel<<<14848, 256, 0, stream>>>(W_in, Wt_in, Wd, Wt_ext, W_out, Wt_out,
                                           B_mat, x, ln_g, ln_b, h_ln, out);
    // 2. xg = h @ W_in   128x128 tile, grid 1024
    gemm_xg<<<dim3(32, 32), 256, 0, stream>>>(h_ln, Wt_in, xg, 4096, 4096, 1024);
    // 3. conv + silu (+delta_acc zero), 8 rows/block
    conv_silu_kernel<<<512, 256, 0, stream>>>(xg, conv_w, conv_b, xsc, delta_acc);
    // 4. delta GEMM + fused Bdot col-block: grid (33,32), rd6 config
    gemm_n64<1><<<dim3(33, 32, 1), 256, 0, stream>>>(xsc, Wt_ext, delta_acc, bd, Bdotn,
                                                     4096, 2048, 2048, 2048);
    // 5. selective scan
    scan_kernel<<<32, 64, 0, stream>>>(delta_acc, Bdotn, A_log, hsn);
    // 6. ymid (into bufA; h_ln/Wt_in dead)
    ymid_kernel<<<dim3(8, 4096), 256, 0, stream>>>(hsn, C_mat, D_vec, xsc, xg, ymid);
    // 7. out += ymid @ W_out : rd6 config, split-K=2 atomics, grid 1024
    gemm_n64<4><<<dim3(16, 32, 2), 256, 0, stream>>>(ymid, Wt_out, out, nullptr, nullptr,
                                                     4096, 1024, 2048, 1024);
}

// Round 9
// 363.396 us; speedup vs baseline: 1.0902x; 1.0179x over previous
//
#include <hip/hip_runtime.h>
#include <cstdint>
#include <cstddef>

typedef unsigned short u16;
typedef __attribute__((ext_vector_type(4))) float floatx4;
typedef __attribute__((ext_vector_type(8))) __bf16 bf16x8;

// ---------- bf16 helpers ----------
__device__ __forceinline__ float u2f(u16 u) {
    union { unsigned int i; float f; } x;
    x.i = ((unsigned int)u) << 16;
    return x.f;
}
__device__ __forceinline__ u16 f2u(float f) {
    union { float f; unsigned int i; } x;
    x.f = f;
    unsigned int r = x.i + 0x7fffu + ((x.i >> 16) & 1u);   // RNE
    return (u16)(r >> 16);
}

// ---------- prep: 3 weight transposes + B_mat cast-copy/pad + layernorm(+out=x) ----------
__device__ __forceinline__ void tr_tile(const float* __restrict__ in, u16* __restrict__ out,
                                        int K, int N, int bx, int by, float* tile /*32x33*/) {
    int n0 = bx * 32, k0 = by * 32;
    int tx = threadIdx.x & 31, ty = threadIdx.x >> 5;   // ty 0..7
#pragma unroll
    for (int j = 0; j < 4; ++j) {
        int r = ty + j * 8;
        tile[r * 33 + tx] = in[(size_t)(k0 + r) * N + n0 + tx];
    }
    __syncthreads();
#pragma unroll
    for (int j = 0; j < 4; ++j) {
        int r = ty + j * 8;
        out[(size_t)(n0 + r) * K + k0 + tx] = f2u(tile[tx * 33 + r]);
    }
}

// blocks: [0,4096) W_in tr; [4096,8192) Wd tr (rows 0..2047 of Wt_ext);
//         [8192,10240) W_out tr; [10240,14336) layernorm; [14336,14848) B_mat copy+pad
__global__ __launch_bounds__(256)
void prep_kernel(const float* __restrict__ W_in, u16* __restrict__ Wt_in,
                 const float* __restrict__ Wd, u16* __restrict__ Wt_ext,
                 const float* __restrict__ W_out, u16* __restrict__ Wt_out,
                 const float* __restrict__ B_mat,
                 const float* __restrict__ x, const float* __restrict__ gamma,
                 const float* __restrict__ beta, u16* __restrict__ h,
                 float* __restrict__ out) {
    __shared__ float tile[32 * 33];
    int blk = blockIdx.x, t = threadIdx.x;
    if (blk < 4096) {
        tr_tile(W_in, Wt_in, 1024, 4096, blk & 127, blk >> 7, tile);
    } else if (blk < 8192) {
        int b2 = blk - 4096;
        tr_tile(Wd, Wt_ext, 2048, 2048, b2 & 63, b2 >> 6, tile);
    } else if (blk < 10240) {
        int b3 = blk - 8192;
        tr_tile(W_out, Wt_out, 2048, 1024, b3 & 31, b3 >> 5, tile);
    } else if (blk < 14336) {
        int r = blk - 10240;
        const float4* xr = (const float4*)(x + (size_t)r * 1024);
        float4 xv = xr[t];
        ((float4*)(out + (size_t)r * 1024))[t] = xv;   // residual base for atomic GEMM3
        float s = xv.x + xv.y + xv.z + xv.w;
        float ss = xv.x * xv.x + xv.y * xv.y + xv.z * xv.z + xv.w * xv.w;
#pragma unroll
        for (int off = 32; off > 0; off >>= 1) {
            s += __shfl_down(s, off, 64);
            ss += __shfl_down(ss, off, 64);
        }
        __shared__ float rs[4], rss[4], mu_s, ri_s;
        int wave = t >> 6, lane = t & 63;
        if (lane == 0) { rs[wave] = s; rss[wave] = ss; }
        __syncthreads();
        if (t == 0) {
            float S = rs[0] + rs[1] + rs[2] + rs[3];
            float SS = rss[0] + rss[1] + rss[2] + rss[3];
            float mu = S * (1.f / 1024.f);
            float var = SS * (1.f / 1024.f) - mu * mu;
            mu_s = mu;
            ri_s = rsqrtf(fmaxf(var, 0.f) + 1e-5f);
        }
        __syncthreads();
        float mu = mu_s, ri = ri_s;
        float4 gv = ((const float4*)gamma)[t];
        float4 bv = ((const float4*)beta)[t];
        ushort4 o;
        o.x = f2u((xv.x - mu) * ri * gv.x + bv.x);
        o.y = f2u((xv.y - mu) * ri * gv.y + bv.y);
        o.z = f2u((xv.z - mu) * ri * gv.z + bv.z);
        o.w = f2u((xv.w - mu) * ri * gv.w + bv.w);
        ((ushort4*)(h + (size_t)r * 1024))[t] = o;
    } else {
        // Wt_ext rows 2048..2111: first 16 = B_mat (bf16 cast), rest zero pad
        int idx = (blk - 14336) * 256 + t;         // 0..131071
        int row = 2048 + (idx >> 11), col = idx & 2047;
        u16 v = (row < 2064) ? f2u(B_mat[(size_t)(row - 2048) * 2048 + col]) : (u16)0;
        Wt_ext[(size_t)row * 2048 + col] = v;
    }
}

__device__ __forceinline__ void gl_lds16(const u16* g, u16* l) {
    __builtin_amdgcn_global_load_lds(
        (const __attribute__((address_space(1))) void*)g,
        (__attribute__((address_space(3))) void*)l, 16, 0, 0);
}

// ---------- GEMM1 (xg): 128x128 tile, BK=64, 4 waves x (4x4), bf16 store ----------
__global__ __launch_bounds__(256)
void gemm_xg(const u16* __restrict__ A, const u16* __restrict__ Bt,
             u16* __restrict__ out, int M, int N, int K) {
    __shared__ u16 As[128 * 64];
    __shared__ u16 Bs[128 * 64];
    const int tid = threadIdx.x;
    const int wave = tid >> 6, lane = tid & 63;
    const int row0 = blockIdx.y * 128, col0 = blockIdx.x * 128;
    const int l16 = lane & 15, q = lane >> 4;
    const int sRow = lane >> 2, sK = (lane & 3) * 8;

    floatx4 acc[4][4];
#pragma unroll
    for (int i = 0; i < 4; ++i)
#pragma unroll
        for (int j = 0; j < 4; ++j) acc[i][j] = (floatx4){0.f, 0.f, 0.f, 0.f};

    const u16* gA = A + (size_t)(row0 + wave * 32 + sRow) * K + sK;
    const u16* gB = Bt + (size_t)(col0 + wave * 32 + sRow) * K + sK;
    u16* lA = As + wave * 1024;
    u16* lB = Bs + wave * 1024;
    const int rowb = (wave >> 1) * 64, colb = (wave & 1) * 64;

    for (int k0 = 0; k0 < K; k0 += 64) {
#pragma unroll
        for (int h = 0; h < 2; ++h) {
            gl_lds16(gA + h * 32, lA + h * 4096);
            gl_lds16(gA + (size_t)16 * K + h * 32, lA + h * 4096 + 512);
            gl_lds16(gB + h * 32, lB + h * 4096);
            gl_lds16(gB + (size_t)16 * K + h * 32, lB + h * 4096 + 512);
        }
        gA += 64; gB += 64;
        __syncthreads();
#pragma unroll
        for (int h = 0; h < 2; ++h) {
            bf16x8 af[4], bfr[4];
#pragma unroll
            for (int mi = 0; mi < 4; ++mi)
                af[mi] = *(const bf16x8*)(As + h * 4096 + (rowb + mi * 16 + l16) * 32 + q * 8);
#pragma unroll
            for (int ni = 0; ni < 4; ++ni)
                bfr[ni] = *(const bf16x8*)(Bs + h * 4096 + (colb + ni * 16 + l16) * 32 + q * 8);
#pragma unroll
            for (int mi = 0; mi < 4; ++mi)
#pragma unroll
                for (int ni = 0; ni < 4; ++ni)
                    acc[mi][ni] = __builtin_amdgcn_mfma_f32_16x16x32_bf16(
                        af[mi], bfr[ni], acc[mi][ni], 0, 0, 0);
        }
        __syncthreads();
    }
    const int mB = row0 + rowb, nB = col0 + colb + l16;
#pragma unroll
    for (int mi = 0; mi < 4; ++mi)
#pragma unroll
        for (int ni = 0; ni < 4; ++ni)
#pragma unroll
            for (int rr = 0; rr < 4; ++rr)
                out[(size_t)(mB + mi * 16 + q * 4 + rr) * N + nB + ni * 16] =
                    f2u(acc[mi][ni][rr]);
}

// ---------- 4-wave GEMM, BK=128, tile 128x64 (LDS 48 KB, 3 blocks/CU) ----------
// EPI 1: delta fusion + Bdot col-block; EPI 4: atomicAdd into out (split-K via z)
template <int EPI>
__device__ __forceinline__
void gemm_n64_body(const u16* __restrict__ A, const u16* __restrict__ Bt,
                   void* __restrict__ out, const void* __restrict__ aux,
                   float* __restrict__ Bdotn,
                   int M, int N, int K, int Ksub) {
    __shared__ u16 As[128 * 128];   // [h][128][32], h=0..3  -> 32 KB
    __shared__ u16 Bs[64 * 128];    // [h][64][32]           -> 16 KB
    const int tid = threadIdx.x;
    const int wave = tid >> 6, lane = tid & 63;
    const int row0 = blockIdx.y * 128, col0 = blockIdx.x * 64;
    const int koff = blockIdx.z * Ksub;
    const int l16 = lane & 15, q = lane >> 4;
    const int sRow = lane >> 2, sK = (lane & 3) * 8;

    floatx4 acc[2][4];
#pragma unroll
    for (int i = 0; i < 2; ++i)
#pragma unroll
        for (int j = 0; j < 4; ++j) acc[i][j] = (floatx4){0.f, 0.f, 0.f, 0.f};

    const u16* gA = A + (size_t)(row0 + wave * 32 + sRow) * K + koff + sK;
    const u16* gB = Bt + (size_t)(col0 + wave * 16 + sRow) * K + koff + sK;
    u16* lA = As + wave * 1024;
    u16* lB = Bs + wave * 512;
    const int rowb = wave * 32;

    for (int k0 = 0; k0 < Ksub; k0 += 128) {
#pragma unroll
        for (int h = 0; h < 4; ++h) {
            gl_lds16(gA + h * 32, lA + h * 4096);
            gl_lds16(gA + (size_t)16 * K + h * 32, lA + h * 4096 + 512);
            gl_lds16(gB + h * 32, lB + h * 2048);
        }
        gA += 128; gB += 128;
        __syncthreads();
#pragma unroll
        for (int h = 0; h < 4; ++h) {
            bf16x8 af[2], bfr[4];
#pragma unroll
            for (int mi = 0; mi < 2; ++mi)
                af[mi] = *(const bf16x8*)(As + h * 4096 + (rowb + mi * 16 + l16) * 32 + q * 8);
#pragma unroll
            for (int ni = 0; ni < 4; ++ni)
                bfr[ni] = *(const bf16x8*)(Bs + h * 2048 + (ni * 16 + l16) * 32 + q * 8);
#pragma unroll
            for (int mi = 0; mi < 2; ++mi)
#pragma unroll
                for (int ni = 0; ni < 4; ++ni)
                    acc[mi][ni] = __builtin_amdgcn_mfma_f32_16x16x32_bf16(
                        af[mi], bfr[ni], acc[mi][ni], 0, 0, 0);
        }
        __syncthreads();
    }

    const int mB = row0 + rowb;
    const int nB = col0 + l16;
    if constexpr (EPI == 1) {
        if (col0 < 2048) {
            float* dacc = (float*)out;
            const float* bias = (const float*)aux;
#pragma unroll
            for (int mi = 0; mi < 2; ++mi) {
#pragma unroll
                for (int rr = 0; rr < 4; ++rr) {
                    float sv = 0.f;
#pragma unroll
                    for (int ni = 0; ni < 4; ++ni) {
                        float t2 = acc[mi][ni][rr] + bias[nB + ni * 16];
                        sv += (t2 > 20.f) ? t2 : log1pf(expf(t2));
                    }
#pragma unroll
                    for (int off = 1; off < 16; off <<= 1)
                        sv += __shfl_xor(sv, off, 64);
                    if (l16 == 0)
                        atomicAdd(&dacc[mB + mi * 16 + q * 4 + rr], sv);
                }
            }
        } else {
            // Bdot col-block: local n = l16 (ni==0 only); raw dot, n-major store
#pragma unroll
            for (int mi = 0; mi < 2; ++mi)
#pragma unroll
                for (int rr = 0; rr < 4; ++rr)
                    Bdotn[(size_t)l16 * 4096 + mB + mi * 16 + q * 4 + rr] =
                        acc[mi][0][rr];
        }
    } else {
        float* C = (float*)out;
#pragma unroll
        for (int mi = 0; mi < 2; ++mi)
#pragma unroll
            for (int ni = 0; ni < 4; ++ni)
#pragma unroll
                for (int rr = 0; rr < 4; ++rr)
                    atomicAdd(&C[(size_t)(mB + mi * 16 + q * 4 + rr) * N + nB + ni * 16],
                              acc[mi][ni][rr]);
    }
}

__global__ __launch_bounds__(256)
void gemm_delta(const u16* __restrict__ A, const u16* __restrict__ Bt,
                void* __restrict__ out, const void* __restrict__ aux,
                float* __restrict__ Bdotn, int M, int N, int K, int Ksub) {
    gemm_n64_body<1>(A, Bt, out, aux, Bdotn, M, N, K, Ksub);
}

__global__ __launch_bounds__(256)
void gemm_fin(const u16* __restrict__ A, const u16* __restrict__ Bt,
              void* __restrict__ out, const void* __restrict__ aux,
              float* __restrict__ Bdotn, int M, int N, int K, int Ksub) {
    gemm_n64_body<4>(A, Bt, out, aux, Bdotn, M, N, K, Ksub);
}

// ---------- lean conv(K=4)+SiLU, 8 rows/block + delta_acc zero ----------
__global__ __launch_bounds__(256) void conv_silu_kernel(const u16* __restrict__ xg,
                                                        const float* __restrict__ conv_w,
                                                        const float* __restrict__ conv_b,
                                                        u16* __restrict__ xsc,
                                                        float* __restrict__ delta_acc) {
    int r0 = blockIdx.x * 8;                  // 8 rows/block; 2048 % 8 == 0
    int l0 = r0 & 2047, bb = r0 >> 11;
    int t = threadIdx.x, d8 = t * 8;
    if (t < 8) delta_acc[r0 + t] = 0.f;       // zero before gemm_delta's atomics

    ushort4 rw[11][2];
#pragma unroll
    for (int j = 0; j < 11; ++j) {
        int ls = l0 + j - 3;
        if (ls >= 0) {
            const u16* row = xg + (size_t)((bb << 11) + ls) * 4096 + d8;
            rw[j][0] = *(const ushort4*)row;
            rw[j][1] = *(const ushort4*)(row + 4);
        } else {
            rw[j][0] = (ushort4){0, 0, 0, 0};
            rw[j][1] = (ushort4){0, 0, 0, 0};
        }
    }
    float w[8][4];
#pragma unroll
    for (int j = 0; j < 8; ++j) {
        float4 wv = *(const float4*)(conv_w + (size_t)(d8 + j) * 4);
        w[j][0] = wv.x; w[j][1] = wv.y; w[j][2] = wv.z; w[j][3] = wv.w;
    }
    float cb[8];
    {
        float4 b0 = *(const float4*)(conv_b + d8);
        float4 b1 = *(const float4*)(conv_b + d8 + 4);
        cb[0] = b0.x; cb[1] = b0.y; cb[2] = b0.z; cb[3] = b0.w;
        cb[4] = b1.x; cb[5] = b1.y; cb[6] = b1.z; cb[7] = b1.w;
    }
#pragma unroll
    for (int i = 0; i < 8; ++i) {
        float xs[8];
#pragma unroll
        for (int j = 0; j < 8; ++j) xs[j] = cb[j];
#pragma unroll
        for (int k = 0; k < 4; ++k) {
            ushort4 u0 = rw[i + k][0], u1 = rw[i + k][1];
            xs[0] += w[0][k] * u2f(u0.x); xs[1] += w[1][k] * u2f(u0.y);
            xs[2] += w[2][k] * u2f(u0.z); xs[3] += w[3][k] * u2f(u0.w);
            xs[4] += w[4][k] * u2f(u1.x); xs[5] += w[5][k] * u2f(u1.y);
            xs[6] += w[6][k] * u2f(u1.z); xs[7] += w[7][k] * u2f(u1.w);
        }
        ushort4 o0, o1;
        o0.x = f2u(xs[0] / (1.f + expf(-xs[0])));
        o0.y = f2u(xs[1] / (1.f + expf(-xs[1])));
        o0.z = f2u(xs[2] / (1.f + expf(-xs[2])));
        o0.w = f2u(xs[3] / (1.f + expf(-xs[3])));
        o1.x = f2u(xs[4] / (1.f + expf(-xs[4])));
        o1.y = f2u(xs[5] / (1.f + expf(-xs[5])));
        o1.z = f2u(xs[6] / (1.f + expf(-xs[6])));
        o1.w = f2u(xs[7] / (1.f + expf(-xs[7])));
        u16* orow = xsc + (size_t)(r0 + i) * 2048 + d8;
        *(ushort4*)orow = o0;
        *(ushort4*)(orow + 4) = o1;
    }
}

// ---------- selective scan: 32 chains, 1 wave each; n-major I/O, LDS-coalesced ----------
__global__ __launch_bounds__(64) void scan_kernel(const float* __restrict__ delta_acc,
                                                  const float* __restrict__ Bdotn,
                                                  const float* __restrict__ A_log,
                                                  float* __restrict__ hsn) {
    int chain = blockIdx.x;                 // 0..31
    int b = chain >> 4, n = chain & 15;
    int j = threadIdx.x;                    // 0..63
    __shared__ float sd[2048], sb[2048];
#pragma unroll
    for (int m = 0; m < 8; ++m) {
        int idx = (m * 64 + j) * 4;
        *(float4*)(sd + idx) = *(const float4*)(delta_acc + b * 2048 + idx);
        *(float4*)(sb + idx) = *(const float4*)(Bdotn + (size_t)n * 4096 + b * 2048 + idx);
    }
    __syncthreads();
    float An = -expf(A_log[n]);
    float a[32], bb[32];
#pragma unroll
    for (int i = 0; i < 32; ++i) {
        float dl = sd[j * 32 + i] * (1.f / 2048.f);
        a[i] = expf(dl * An);
        bb[i] = sb[j * 32 + i] * dl;
    }
    float Aacc = 1.f, Bacc = 0.f;
#pragma unroll
    for (int i = 0; i < 32; ++i) {
        Bacc = a[i] * Bacc + bb[i];
        Aacc = a[i] * Aacc;
    }
#pragma unroll
    for (int d = 1; d < 64; d <<= 1) {
        float Ap = __shfl_up(Aacc, d, 64);
        float Bp = __shfl_up(Bacc, d, 64);
        if (j >= d) {
            Bacc = Aacc * Bp + Bacc;
            Aacc = Aacc * Ap;
        }
    }
    float hstart = __shfl_up(Bacc, 1, 64);
    if (j == 0) hstart = 0.f;
    float h = hstart;
    __syncthreads();
#pragma unroll
    for (int i = 0; i < 32; ++i) {
        h = a[i] * h + bb[i];
        sd[j * 32 + i] = h;
    }
    __syncthreads();
#pragma unroll
    for (int m = 0; m < 8; ++m) {
        int idx = (m * 64 + j) * 4;
        *(float4*)(hsn + (size_t)n * 4096 + b * 2048 + idx) = *(const float4*)(sd + idx);
    }
}

// ---------- ymid = (hs·C_mat[d,:] + D_vec*xsc) * silu(gate), bf16 out ----------
__global__ __launch_bounds__(256) void ymid_kernel(const float* __restrict__ hsn,
                                                   const float* __restrict__ C_mat,
                                                   const float* __restrict__ D_vec,
                                                   const u16* __restrict__ xsc,
                                                   const u16* __restrict__ xg,
                                                   u16* __restrict__ ymid) {
    int r = blockIdx.y;
    int d = blockIdx.x * 256 + threadIdx.x;
    __shared__ float hsv[16];
    if (threadIdx.x < 16) hsv[threadIdx.x] = hsn[(size_t)threadIdx.x * 4096 + r];
    __syncthreads();
    const float* crow = C_mat + (size_t)d * 16;
    float acc = 0.f;
#pragma unroll
    for (int n = 0; n < 16; ++n) acc += hsv[n] * crow[n];
    float xv = u2f(xsc[(size_t)r * 2048 + d]);
    float g = u2f(xg[(size_t)r * 4096 + 2048 + d]);
    float y = acc + D_vec[d] * xv;
    y *= g / (1.f + expf(-g));
    ymid[(size_t)r * 2048 + d] = f2u(y);
}

extern "C" void kernel_launch(void* const* d_in, const int* in_sizes, int n_in,
                              void* d_out, int out_size, void* d_ws, size_t ws_size,
                              hipStream_t stream) {
    (void)in_sizes; (void)n_in;
    const float* x      = (const float*)d_in[0];
    const float* ln_g   = (const float*)d_in[1];
    const float* ln_b   = (const float*)d_in[2];
    const float* W_in   = (const float*)d_in[3];
    const float* conv_w = (const float*)d_in[4];
    const float* conv_b = (const float*)d_in[5];
    const float* A_log  = (const float*)d_in[6];
    const float* B_mat  = (const float*)d_in[7];
    const float* C_mat  = (const float*)d_in[8];
    const float* D_vec  = (const float*)d_in[9];
    const float* Wd     = (const float*)d_in[10];
    const float* bd     = (const float*)d_in[11];
    const float* W_out  = (const float*)d_in[12];
    float* out = (float*)d_out;

    // ---- workspace layout (time-overlaid), ~77.1 MiB ----
    char* base = (char*)d_ws;
    u16* Wt_in  = (u16*)base;                          // 4096x1024 bf16 (bufA lo)
    u16* h_ln   = (u16*)base + 4096ull * 1024;         // 4096x1024 bf16 (bufA hi)
    u16* ymid   = (u16*)base;                          // 4096x2048 bf16 (reuse bufA post-GEMM1)
    u16* Wt_ext = (u16*)(base + (16ull << 20));        // 2112x2048 bf16 (Wd^T + B_mat + pad)
    u16* Wt_out = (u16*)(base + (25ull << 20));        // 1024x2048 bf16 (4 MiB)
    u16* xg     = (u16*)(base + (29ull << 20));        // 4096x4096 bf16 (32 MiB)
    u16* xsc    = (u16*)(base + (61ull << 20));        // 4096x2048 bf16 (16 MiB)
    float* delta_acc = (float*)(base + (77ull << 20)); // 4096 f32
    float* Bdotn = delta_acc + 4096;                   // [16][4096] f32
    float* hsn   = Bdotn + 16 * 4096;                  // [16][4096] f32
    size_t needed = (77ull << 20) + 4096ull * 4 * (1 + 2 * 16);

    if (needed > ws_size) {
        hipMemsetAsync(d_out, 0x7F, (size_t)out_size * 4, stream);  // finite sentinel 3.39e38
        return;
    }

    // 1. prep: transposes + B_mat rows + layernorm + out=x
    prep_kernel<<<14848, 256, 0, stream>>>(W_in, Wt_in, Wd, Wt_ext, W_out, Wt_out,
                                           B_mat, x, ln_g, ln_b, h_ln, out);
    // 2. xg = h @ W_in   128x128 tile, grid 1024
    gemm_xg<<<dim3(32, 32), 256, 0, stream>>>(h_ln, Wt_in, xg, 4096, 4096, 1024);
    // 3. conv + silu (+delta_acc zero), 8 rows/block
    conv_silu_kernel<<<512, 256, 0, stream>>>(xg, conv_w, conv_b, xsc, delta_acc);
    // 4. delta GEMM + fused Bdot col-block: grid (33,32), BK=128
    gemm_delta<<<dim3(33, 32, 1), 256, 0, stream>>>(xsc, Wt_ext, delta_acc, bd, Bdotn,
                                                    4096, 2048, 2048, 2048);
    // 5. selective scan
    scan_kernel<<<32, 64, 0, stream>>>(delta_acc, Bdotn, A_log, hsn);
    // 6. ymid (into bufA; h_ln/Wt_in dead)
    ymid_kernel<<<dim3(8, 4096), 256, 0, stream>>>(hsn, C_mat, D_vec, xsc, xg, ymid);
    // 7. out += ymid @ W_out : BK=128, split-K=2 atomics, grid 1024
    gemm_fin<<<dim3(16, 32, 2), 256, 0, stream>>>(ymid, Wt_out, out, nullptr, nullptr,
                                                  4096, 1024, 2048, 1024);
}

// Round 10
// 348.944 us; speedup vs baseline: 1.1354x; 1.0414x over previous
//
#include <hip/hip_runtime.h>
#include <cstdint>
#include <cstddef>

typedef unsigned short u16;
typedef __attribute__((ext_vector_type(4))) float floatx4;
typedef __attribute__((ext_vector_type(8))) __bf16 bf16x8;

// ---------- bf16 helpers ----------
__device__ __forceinline__ float u2f(u16 u) {
    union { unsigned int i; float f; } x;
    x.i = ((unsigned int)u) << 16;
    return x.f;
}
__device__ __forceinline__ u16 f2u(float f) {
    union { float f; unsigned int i; } x;
    x.f = f;
    unsigned int r = x.i + 0x7fffu + ((x.i >> 16) & 1u);   // RNE
    return (u16)(r >> 16);
}

// ---------- XCD-aware swizzle: bid -> (x,y); XCD k owns y-strip [4k,4k+4), x-major ----------
// grid must be nx*32 blocks, nx*32 % 8 == 0. Bijection: bid%8 -> strip, bid/8 -> (x, y_in).
__device__ __forceinline__ void swz(int bid, int& x, int& y) {
    int xcd = bid & 7;
    int lid = bid >> 3;
    x = lid >> 2;
    y = xcd * 4 + (lid & 3);
}

// ---------- prep: 3 weight transposes + B_mat cast-copy/pad + layernorm(+out=x) ----------
__device__ __forceinline__ void tr_tile(const float* __restrict__ in, u16* __restrict__ out,
                                        int K, int N, int bx, int by, float* tile /*32x33*/) {
    int n0 = bx * 32, k0 = by * 32;
    int tx = threadIdx.x & 31, ty = threadIdx.x >> 5;   // ty 0..7
#pragma unroll
    for (int j = 0; j < 4; ++j) {
        int r = ty + j * 8;
        tile[r * 33 + tx] = in[(size_t)(k0 + r) * N + n0 + tx];
    }
    __syncthreads();
#pragma unroll
    for (int j = 0; j < 4; ++j) {
        int r = ty + j * 8;
        out[(size_t)(n0 + r) * K + k0 + tx] = f2u(tile[tx * 33 + r]);
    }
}

// blocks: [0,4096) W_in tr; [4096,8192) Wd tr (rows 0..2047 of Wt_ext);
//         [8192,10240) W_out tr; [10240,14336) layernorm; [14336,14848) B_mat copy+pad
__global__ __launch_bounds__(256)
void prep_kernel(const float* __restrict__ W_in, u16* __restrict__ Wt_in,
                 const float* __restrict__ Wd, u16* __restrict__ Wt_ext,
                 const float* __restrict__ W_out, u16* __restrict__ Wt_out,
                 const float* __restrict__ B_mat,
                 const float* __restrict__ x, const float* __restrict__ gamma,
                 const float* __restrict__ beta, u16* __restrict__ h,
                 float* __restrict__ out) {
    __shared__ float tile[32 * 33];
    int blk = blockIdx.x, t = threadIdx.x;
    if (blk < 4096) {
        tr_tile(W_in, Wt_in, 1024, 4096, blk & 127, blk >> 7, tile);
    } else if (blk < 8192) {
        int b2 = blk - 4096;
        tr_tile(Wd, Wt_ext, 2048, 2048, b2 & 63, b2 >> 6, tile);
    } else if (blk < 10240) {
        int b3 = blk - 8192;
        tr_tile(W_out, Wt_out, 2048, 1024, b3 & 31, b3 >> 5, tile);
    } else if (blk < 14336) {
        int r = blk - 10240;
        const float4* xr = (const float4*)(x + (size_t)r * 1024);
        float4 xv = xr[t];
        ((float4*)(out + (size_t)r * 1024))[t] = xv;   // residual base for atomic GEMM3
        float s = xv.x + xv.y + xv.z + xv.w;
        float ss = xv.x * xv.x + xv.y * xv.y + xv.z * xv.z + xv.w * xv.w;
#pragma unroll
        for (int off = 32; off > 0; off >>= 1) {
            s += __shfl_down(s, off, 64);
            ss += __shfl_down(ss, off, 64);
        }
        __shared__ float rs[4], rss[4], mu_s, ri_s;
        int wave = t >> 6, lane = t & 63;
        if (lane == 0) { rs[wave] = s; rss[wave] = ss; }
        __syncthreads();
        if (t == 0) {
            float S = rs[0] + rs[1] + rs[2] + rs[3];
            float SS = rss[0] + rss[1] + rss[2] + rss[3];
            float mu = S * (1.f / 1024.f);
            float var = SS * (1.f / 1024.f) - mu * mu;
            mu_s = mu;
            ri_s = rsqrtf(fmaxf(var, 0.f) + 1e-5f);
        }
        __syncthreads();
        float mu = mu_s, ri = ri_s;
        float4 gv = ((const float4*)gamma)[t];
        float4 bv = ((const float4*)beta)[t];
        ushort4 o;
        o.x = f2u((xv.x - mu) * ri * gv.x + bv.x);
        o.y = f2u((xv.y - mu) * ri * gv.y + bv.y);
        o.z = f2u((xv.z - mu) * ri * gv.z + bv.z);
        o.w = f2u((xv.w - mu) * ri * gv.w + bv.w);
        ((ushort4*)(h + (size_t)r * 1024))[t] = o;
    } else {
        // Wt_ext rows 2048..2111: first 16 = B_mat (bf16 cast), rest zero pad
        int idx = (blk - 14336) * 256 + t;         // 0..131071
        int row = 2048 + (idx >> 11), col = idx & 2047;
        u16 v = (row < 2064) ? f2u(B_mat[(size_t)(row - 2048) * 2048 + col]) : (u16)0;
        Wt_ext[(size_t)row * 2048 + col] = v;
    }
}

__device__ __forceinline__ void gl_lds16(const u16* g, u16* l) {
    __builtin_amdgcn_global_load_lds(
        (const __attribute__((address_space(1))) void*)g,
        (__attribute__((address_space(3))) void*)l, 16, 0, 0);
}

// ---------- GEMM1 (xg): 128x128 tile, BK=64, 4 waves x (4x4), bf16 store ----------
// 1D grid (nx=32, ny=32), XCD-swizzled
__global__ __launch_bounds__(256)
void gemm_xg(const u16* __restrict__ A, const u16* __restrict__ Bt,
             u16* __restrict__ out, int M, int N, int K) {
    __shared__ u16 As[128 * 64];
    __shared__ u16 Bs[128 * 64];
    int bx, by;
    swz(blockIdx.x, bx, by);
    const int tid = threadIdx.x;
    const int wave = tid >> 6, lane = tid & 63;
    const int row0 = by * 128, col0 = bx * 128;
    const int l16 = lane & 15, q = lane >> 4;
    const int sRow = lane >> 2, sK = (lane & 3) * 8;

    floatx4 acc[4][4];
#pragma unroll
    for (int i = 0; i < 4; ++i)
#pragma unroll
        for (int j = 0; j < 4; ++j) acc[i][j] = (floatx4){0.f, 0.f, 0.f, 0.f};

    const u16* gA = A + (size_t)(row0 + wave * 32 + sRow) * K + sK;
    const u16* gB = Bt + (size_t)(col0 + wave * 32 + sRow) * K + sK;
    u16* lA = As + wave * 1024;
    u16* lB = Bs + wave * 1024;
    const int rowb = (wave >> 1) * 64, colb = (wave & 1) * 64;

    for (int k0 = 0; k0 < K; k0 += 64) {
#pragma unroll
        for (int h = 0; h < 2; ++h) {
            gl_lds16(gA + h * 32, lA + h * 4096);
            gl_lds16(gA + (size_t)16 * K + h * 32, lA + h * 4096 + 512);
            gl_lds16(gB + h * 32, lB + h * 4096);
            gl_lds16(gB + (size_t)16 * K + h * 32, lB + h * 4096 + 512);
        }
        gA += 64; gB += 64;
        __syncthreads();
#pragma unroll
        for (int h = 0; h < 2; ++h) {
            bf16x8 af[4], bfr[4];
#pragma unroll
            for (int mi = 0; mi < 4; ++mi)
                af[mi] = *(const bf16x8*)(As + h * 4096 + (rowb + mi * 16 + l16) * 32 + q * 8);
#pragma unroll
            for (int ni = 0; ni < 4; ++ni)
                bfr[ni] = *(const bf16x8*)(Bs + h * 4096 + (colb + ni * 16 + l16) * 32 + q * 8);
#pragma unroll
            for (int mi = 0; mi < 4; ++mi)
#pragma unroll
                for (int ni = 0; ni < 4; ++ni)
                    acc[mi][ni] = __builtin_amdgcn_mfma_f32_16x16x32_bf16(
                        af[mi], bfr[ni], acc[mi][ni], 0, 0, 0);
        }
        __syncthreads();
    }
    const int mB = row0 + rowb, nB = col0 + colb + l16;
#pragma unroll
    for (int mi = 0; mi < 4; ++mi)
#pragma unroll
        for (int ni = 0; ni < 4; ++ni)
#pragma unroll
            for (int rr = 0; rr < 4; ++rr)
                out[(size_t)(mB + mi * 16 + q * 4 + rr) * N + nB + ni * 16] =
                    f2u(acc[mi][ni][rr]);
}

// ---------- 4-wave GEMM, BK=128, tile 128x64 (LDS 48 KB), XCD-swizzled 1D grid ----------
// EPI 1: delta fusion + Bdot col-block; EPI 4: atomicAdd into out (split-K via blockIdx.y)
template <int EPI>
__device__ __forceinline__
void gemm_n64_body(const u16* __restrict__ A, const u16* __restrict__ Bt,
                   void* __restrict__ out, const void* __restrict__ aux,
                   float* __restrict__ Bdotn,
                   int M, int N, int K, int Ksub) {
    __shared__ u16 As[128 * 128];   // [h][128][32], h=0..3  -> 32 KB
    __shared__ u16 Bs[64 * 128];    // [h][64][32]           -> 16 KB
    int bx, by;
    swz(blockIdx.x, bx, by);
    const int tid = threadIdx.x;
    const int wave = tid >> 6, lane = tid & 63;
    const int row0 = by * 128, col0 = bx * 64;
    const int koff = blockIdx.y * Ksub;
    const int l16 = lane & 15, q = lane >> 4;
    const int sRow = lane >> 2, sK = (lane & 3) * 8;

    floatx4 acc[2][4];
#pragma unroll
    for (int i = 0; i < 2; ++i)
#pragma unroll
        for (int j = 0; j < 4; ++j) acc[i][j] = (floatx4){0.f, 0.f, 0.f, 0.f};

    const u16* gA = A + (size_t)(row0 + wave * 32 + sRow) * K + koff + sK;
    const u16* gB = Bt + (size_t)(col0 + wave * 16 + sRow) * K + koff + sK;
    u16* lA = As + wave * 1024;
    u16* lB = Bs + wave * 512;
    const int rowb = wave * 32;

    for (int k0 = 0; k0 < Ksub; k0 += 128) {
#pragma unroll
        for (int h = 0; h < 4; ++h) {
            gl_lds16(gA + h * 32, lA + h * 4096);
            gl_lds16(gA + (size_t)16 * K + h * 32, lA + h * 4096 + 512);
            gl_lds16(gB + h * 32, lB + h * 2048);
        }
        gA += 128; gB += 128;
        __syncthreads();
#pragma unroll
        for (int h = 0; h < 4; ++h) {
            bf16x8 af[2], bfr[4];
#pragma unroll
            for (int mi = 0; mi < 2; ++mi)
                af[mi] = *(const bf16x8*)(As + h * 4096 + (rowb + mi * 16 + l16) * 32 + q * 8);
#pragma unroll
            for (int ni = 0; ni < 4; ++ni)
                bfr[ni] = *(const bf16x8*)(Bs + h * 2048 + (ni * 16 + l16) * 32 + q * 8);
#pragma unroll
            for (int mi = 0; mi < 2; ++mi)
#pragma unroll
                for (int ni = 0; ni < 4; ++ni)
                    acc[mi][ni] = __builtin_amdgcn_mfma_f32_16x16x32_bf16(
                        af[mi], bfr[ni], acc[mi][ni], 0, 0, 0);
        }
        __syncthreads();
    }

    const int mB = row0 + rowb;
    const int nB = col0 + l16;
    if constexpr (EPI == 1) {
        if (col0 < 2048) {
            float* dacc = (float*)out;
            const float* bias = (const float*)aux;
#pragma unroll
            for (int mi = 0; mi < 2; ++mi) {
#pragma unroll
                for (int rr = 0; rr < 4; ++rr) {
                    float sv = 0.f;
#pragma unroll
                    for (int ni = 0; ni < 4; ++ni) {
                        float t2 = acc[mi][ni][rr] + bias[nB + ni * 16];
                        sv += (t2 > 20.f) ? t2 : log1pf(expf(t2));
                    }
#pragma unroll
                    for (int off = 1; off < 16; off <<= 1)
                        sv += __shfl_xor(sv, off, 64);
                    if (l16 == 0)
                        atomicAdd(&dacc[mB + mi * 16 + q * 4 + rr], sv);
                }
            }
        } else {
            // Bdot col-block: local n = l16 (ni==0 only); raw dot, n-major store
#pragma unroll
            for (int mi = 0; mi < 2; ++mi)
#pragma unroll
                for (int rr = 0; rr < 4; ++rr)
                    Bdotn[(size_t)l16 * 4096 + mB + mi * 16 + q * 4 + rr] =
                        acc[mi][0][rr];
        }
    } else {
        float* C = (float*)out;
#pragma unroll
        for (int mi = 0; mi < 2; ++mi)
#pragma unroll
            for (int ni = 0; ni < 4; ++ni)
#pragma unroll
                for (int rr = 0; rr < 4; ++rr)
                    atomicAdd(&C[(size_t)(mB + mi * 16 + q * 4 + rr) * N + nB + ni * 16],
                              acc[mi][ni][rr]);
    }
}

__global__ __launch_bounds__(256)
void gemm_delta(const u16* __restrict__ A, const u16* __restrict__ Bt,
                void* __restrict__ out, const void* __restrict__ aux,
                float* __restrict__ Bdotn, int M, int N, int K, int Ksub) {
    gemm_n64_body<1>(A, Bt, out, aux, Bdotn, M, N, K, Ksub);
}

__global__ __launch_bounds__(256)
void gemm_fin(const u16* __restrict__ A, const u16* __restrict__ Bt,
              void* __restrict__ out, const void* __restrict__ aux,
              float* __restrict__ Bdotn, int M, int N, int K, int Ksub) {
    gemm_n64_body<4>(A, Bt, out, aux, Bdotn, M, N, K, Ksub);
}

// ---------- lean conv(K=4)+SiLU, 8 rows/block + delta_acc zero ----------
__global__ __launch_bounds__(256) void conv_silu_kernel(const u16* __restrict__ xg,
                                                        const float* __restrict__ conv_w,
                                                        const float* __restrict__ conv_b,
                                                        u16* __restrict__ xsc,
                                                        float* __restrict__ delta_acc) {
    int r0 = blockIdx.x * 8;                  // 8 rows/block; 2048 % 8 == 0
    int l0 = r0 & 2047, bb = r0 >> 11;
    int t = threadIdx.x, d8 = t * 8;
    if (t < 8) delta_acc[r0 + t] = 0.f;       // zero before gemm_delta's atomics

    ushort4 rw[11][2];
#pragma unroll
    for (int j = 0; j < 11; ++j) {
        int ls = l0 + j - 3;
        if (ls >= 0) {
            const u16* row = xg + (size_t)((bb << 11) + ls) * 4096 + d8;
            rw[j][0] = *(const ushort4*)row;
            rw[j][1] = *(const ushort4*)(row + 4);
        } else {
            rw[j][0] = (ushort4){0, 0, 0, 0};
            rw[j][1] = (ushort4){0, 0, 0, 0};
        }
    }
    float w[8][4];
#pragma unroll
    for (int j = 0; j < 8; ++j) {
        float4 wv = *(const float4*)(conv_w + (size_t)(d8 + j) * 4);
        w[j][0] = wv.x; w[j][1] = wv.y; w[j][2] = wv.z; w[j][3] = wv.w;
    }
    float cb[8];
    {
        float4 b0 = *(const float4*)(conv_b + d8);
        float4 b1 = *(const float4*)(conv_b + d8 + 4);
        cb[0] = b0.x; cb[1] = b0.y; cb[2] = b0.z; cb[3] = b0.w;
        cb[4] = b1.x; cb[5] = b1.y; cb[6] = b1.z; cb[7] = b1.w;
    }
#pragma unroll
    for (int i = 0; i < 8; ++i) {
        float xs[8];
#pragma unroll
        for (int j = 0; j < 8; ++j) xs[j] = cb[j];
#pragma unroll
        for (int k = 0; k < 4; ++k) {
            ushort4 u0 = rw[i + k][0], u1 = rw[i + k][1];
            xs[0] += w[0][k] * u2f(u0.x); xs[1] += w[1][k] * u2f(u0.y);
            xs[2] += w[2][k] * u2f(u0.z); xs[3] += w[3][k] * u2f(u0.w);
            xs[4] += w[4][k] * u2f(u1.x); xs[5] += w[5][k] * u2f(u1.y);
            xs[6] += w[6][k] * u2f(u1.z); xs[7] += w[7][k] * u2f(u1.w);
        }
        ushort4 o0, o1;
        o0.x = f2u(xs[0] / (1.f + expf(-xs[0])));
        o0.y = f2u(xs[1] / (1.f + expf(-xs[1])));
        o0.z = f2u(xs[2] / (1.f + expf(-xs[2])));
        o0.w = f2u(xs[3] / (1.f + expf(-xs[3])));
        o1.x = f2u(xs[4] / (1.f + expf(-xs[4])));
        o1.y = f2u(xs[5] / (1.f + expf(-xs[5])));
        o1.z = f2u(xs[6] / (1.f + expf(-xs[6])));
        o1.w = f2u(xs[7] / (1.f + expf(-xs[7])));
        u16* orow = xsc + (size_t)(r0 + i) * 2048 + d8;
        *(ushort4*)orow = o0;
        *(ushort4*)(orow + 4) = o1;
    }
}

// ---------- selective scan: 32 chains, 1 wave each; n-major I/O, LDS-coalesced ----------
__global__ __launch_bounds__(64) void scan_kernel(const float* __restrict__ delta_acc,
                                                  const float* __restrict__ Bdotn,
                                                  const float* __restrict__ A_log,
                                                  float* __restrict__ hsn) {
    int chain = blockIdx.x;                 // 0..31
    int b = chain >> 4, n = chain & 15;
    int j = threadIdx.x;                    // 0..63
    __shared__ float sd[2048], sb[2048];
#pragma unroll
    for (int m = 0; m < 8; ++m) {
        int idx = (m * 64 + j) * 4;
        *(float4*)(sd + idx) = *(const float4*)(delta_acc + b * 2048 + idx);
        *(float4*)(sb + idx) = *(const float4*)(Bdotn + (size_t)n * 4096 + b * 2048 + idx);
    }
    __syncthreads();
    float An = -expf(A_log[n]);
    float a[32], bb[32];
#pragma unroll
    for (int i = 0; i < 32; ++i) {
        float dl = sd[j * 32 + i] * (1.f / 2048.f);
        a[i] = expf(dl * An);
        bb[i] = sb[j * 32 + i] * dl;
    }
    float Aacc = 1.f, Bacc = 0.f;
#pragma unroll
    for (int i = 0; i < 32; ++i) {
        Bacc = a[i] * Bacc + bb[i];
        Aacc = a[i] * Aacc;
    }
#pragma unroll
    for (int d = 1; d < 64; d <<= 1) {
        float Ap = __shfl_up(Aacc, d, 64);
        float Bp = __shfl_up(Bacc, d, 64);
        if (j >= d) {
            Bacc = Aacc * Bp + Bacc;
            Aacc = Aacc * Ap;
        }
    }
    float hstart = __shfl_up(Bacc, 1, 64);
    if (j == 0) hstart = 0.f;
    float h = hstart;
    __syncthreads();
#pragma unroll
    for (int i = 0; i < 32; ++i) {
        h = a[i] * h + bb[i];
        sd[j * 32 + i] = h;
    }
    __syncthreads();
#pragma unroll
    for (int m = 0; m < 8; ++m) {
        int idx = (m * 64 + j) * 4;
        *(float4*)(hsn + (size_t)n * 4096 + b * 2048 + idx) = *(const float4*)(sd + idx);
    }
}

// ---------- ymid = (hs·C_mat[d,:] + D_vec*xsc) * silu(gate), bf16 out ----------
__global__ __launch_bounds__(256) void ymid_kernel(const float* __restrict__ hsn,
                                                   const float* __restrict__ C_mat,
                                                   const float* __restrict__ D_vec,
                                                   const u16* __restrict__ xsc,
                                                   const u16* __restrict__ xg,
                                                   u16* __restrict__ ymid) {
    int r = blockIdx.y;
    int d = blockIdx.x * 256 + threadIdx.x;
    __shared__ float hsv[16];
    if (threadIdx.x < 16) hsv[threadIdx.x] = hsn[(size_t)threadIdx.x * 4096 + r];
    __syncthreads();
    const float* crow = C_mat + (size_t)d * 16;
    float acc = 0.f;
#pragma unroll
    for (int n = 0; n < 16; ++n) acc += hsv[n] * crow[n];
    float xv = u2f(xsc[(size_t)r * 2048 + d]);
    float g = u2f(xg[(size_t)r * 4096 + 2048 + d]);
    float y = acc + D_vec[d] * xv;
    y *= g / (1.f + expf(-g));
    ymid[(size_t)r * 2048 + d] = f2u(y);
}

extern "C" void kernel_launch(void* const* d_in, const int* in_sizes, int n_in,
                              void* d_out, int out_size, void* d_ws, size_t ws_size,
                              hipStream_t stream) {
    (void)in_sizes; (void)n_in;
    const float* x      = (const float*)d_in[0];
    const float* ln_g   = (const float*)d_in[1];
    const float* ln_b   = (const float*)d_in[2];
    const float* W_in   = (const float*)d_in[3];
    const float* conv_w = (const float*)d_in[4];
    const float* conv_b = (const float*)d_in[5];
    const float* A_log  = (const float*)d_in[6];
    const float* B_mat  = (const float*)d_in[7];
    const float* C_mat  = (const float*)d_in[8];
    const float* D_vec  = (const float*)d_in[9];
    const float* Wd     = (const float*)d_in[10];
    const float* bd     = (const float*)d_in[11];
    const float* W_out  = (const float*)d_in[12];
    float* out = (float*)d_out;

    // ---- workspace layout (time-overlaid), ~77.1 MiB ----
    char* base = (char*)d_ws;
    u16* Wt_in  = (u16*)base;                          // 4096x1024 bf16 (bufA lo)
    u16* h_ln   = (u16*)base + 4096ull * 1024;         // 4096x1024 bf16 (bufA hi)
    u16* ymid   = (u16*)base;                          // 4096x2048 bf16 (reuse bufA post-GEMM1)
    u16* Wt_ext = (u16*)(base + (16ull << 20));        // 2112x2048 bf16 (Wd^T + B_mat + pad)
    u16* Wt_out = (u16*)(base + (25ull << 20));        // 1024x2048 bf16 (4 MiB)
    u16* xg     = (u16*)(base + (29ull << 20));        // 4096x4096 bf16 (32 MiB)
    u16* xsc    = (u16*)(base + (61ull << 20));        // 4096x2048 bf16 (16 MiB)
    float* delta_acc = (float*)(base + (77ull << 20)); // 4096 f32
    float* Bdotn = delta_acc + 4096;                   // [16][4096] f32
    float* hsn   = Bdotn + 16 * 4096;                  // [16][4096] f32
    size_t needed = (77ull << 20) + 4096ull * 4 * (1 + 2 * 16);

    if (needed > ws_size) {
        hipMemsetAsync(d_out, 0x7F, (size_t)out_size * 4, stream);  // finite sentinel 3.39e38
        return;
    }

    // 1. prep: transposes + B_mat rows + layernorm + out=x
    prep_kernel<<<14848, 256, 0, stream>>>(W_in, Wt_in, Wd, Wt_ext, W_out, Wt_out,
                                           B_mat, x, ln_g, ln_b, h_ln, out);
    // 2. xg = h @ W_in   128x128 tile, XCD-swizzled 1D grid (nx=32, ny=32)
    gemm_xg<<<1024, 256, 0, stream>>>(h_ln, Wt_in, xg, 4096, 4096, 1024);
    // 3. conv + silu (+delta_acc zero), 8 rows/block
    conv_silu_kernel<<<512, 256, 0, stream>>>(xg, conv_w, conv_b, xsc, delta_acc);
    // 4. delta GEMM + fused Bdot col-block: XCD-swizzled (nx=33, ny=32), BK=128
    gemm_delta<<<1056, 256, 0, stream>>>(xsc, Wt_ext, delta_acc, bd, Bdotn,
                                         4096, 2048, 2048, 2048);
    // 5. selective scan
    scan_kernel<<<32, 64, 0, stream>>>(delta_acc, Bdotn, A_log, hsn);
    // 6. ymid (into bufA; h_ln/Wt_in dead)
    ymid_kernel<<<dim3(8, 4096), 256, 0, stream>>>(hsn, C_mat, D_vec, xsc, xg, ymid);
    // 7. out += ymid @ W_out : XCD-swizzled (nx=16, ny=32), split-K=2 (blockIdx.y) atomics
    gemm_fin<<<dim3(512, 2), 256, 0, stream>>>(ymid, Wt_out, out, nullptr, nullptr,
                                               4096, 1024, 2048, 1024);
}